// Round 9
// baseline (120.950 us; speedup 1.0000x reference)
//
#include <hip/hip_runtime.h>

#define LAMB_COORD 5.0f
#define LAMB_NOOBJ 0.5f
#define GEPS 1e-7f

// gt/pred: (B=16384, C=30, H=7, W=7) fp32. Record = 1470 floats = 30ch x 49 cells.
// Block = 256 threads owns 2 consecutive records (2940 floats, 11760 B, base
// 16B-aligned, 735 float4 per array).
//   Stage:  g+p spans -> LDS via __builtin_amdgcn_global_load_lds width=16
//           (dwordx4 direct to LDS: no VGPR round-trip, all 6 insts in flight,
//           one counted drain). Linear dest = the builtin's required layout.
//   Cells:  98 threads compute per-cell GIoU/argmax/front loss from LDS
//           (stride-49 ds reads, <=2-way aliasing), app[98] -> LDS.
//   Class:  all 256 threads consume 980 class float2 from LDS (ds_read_b64,
//           2-way = free) with app mask; hw = (2q) mod 49 (980 = 20*49).
//   Reduce: wave shuffle -> LDS -> one atomic per block.

typedef __attribute__((address_space(3))) void lds_void_t;
typedef __attribute__((address_space(1))) const void gvoid_t;

__device__ __forceinline__ void gload_lds16(const void* g, void* l) {
    __builtin_amdgcn_global_load_lds((gvoid_t*)g, (lds_void_t*)l, 16, 0, 0);
}

#define RECF   1470
#define SPANF  (2 * RECF)       // 2940 floats per array per block
#define SPAN4  (SPANF / 4)      // 735 float4
#define CELLS  98
#define CLS2   980              // class float2 per block (2 records x 490)

__global__ __launch_bounds__(256) void yolo_loss_kernel(
        const float* __restrict__ gt, const float* __restrict__ pred,
        float* __restrict__ out) {
    __shared__ float lg[SPANF];
    __shared__ float lp[SPANF];
    __shared__ float app[CELLS];
    __shared__ float wsum[4];

    const int tid = threadIdx.x;
    const size_t base = (size_t)blockIdx.x * SPANF;
    const float4* __restrict__ g4 = (const float4*)(gt + base);
    const float4* __restrict__ p4 = (const float4*)(pred + base);

    // ---- Stage: 735 float4 per array, direct to LDS ----
    #pragma unroll
    for (int k = 0; k < 3; ++k) {
        int idx = tid + k * 256;
        if (idx < SPAN4) {
            gload_lds16(g4 + idx, ((float4*)lg) + idx);
            gload_lds16(p4 + idx, ((float4*)lp) + idx);
        }
    }
    asm volatile("s_waitcnt vmcnt(0)" ::: "memory");
    __syncthreads();

    // ---- Cells: per-cell front loss (exact R7 formulas) ----
    float s = 0.0f;
    if (tid < CELLS) {
        const int rr = (tid >= 49) ? 1 : 0;
        const int hw = tid - rr * 49;
        const float* __restrict__ g = lg + rr * RECF + hw;
        const float* __restrict__ p = lp + rr * RECF + hw;

        float gv[10], pv[10];
        #pragma unroll
        for (int c = 0; c < 10; ++c) { gv[c] = g[c * 49]; pv[c] = p[c * 49]; }

        const float gx1 = gv[0], gy1 = gv[1];
        const float gx2 = gv[0] + gv[2], gy2 = gv[1] + gv[3];
        const float ga  = (gx2 - gx1) * (gy2 - gy1);

        float l[2];
        #pragma unroll
        for (int k = 0; k < 2; ++k) {
            const int o = k * 5;
            float px1 = pv[o + 0], py1 = pv[o + 1];
            float px2 = px1 + pv[o + 2], py2 = py1 + pv[o + 3];
            float ix1 = fmaxf(gx1, px1), iy1 = fmaxf(gy1, py1);
            float ix2 = fminf(gx2, px2), iy2 = fminf(gy2, py2);
            float inter = fmaxf(ix2 - ix1, 0.0f) * fmaxf(iy2 - iy1, 0.0f);
            float pa  = (px2 - px1) * (py2 - py1);
            float uni = ga + pa - inter;
            float iou = inter / (uni + GEPS);
            float cx1 = fminf(gx1, px1), cy1 = fminf(gy1, py1);
            float cx2 = fmaxf(gx2, px2), cy2 = fmaxf(gy2, py2);
            float enc = (cx2 - cx1) * (cy2 - cy1);
            l[k] = 1.0f - (iou - (enc - uni) / (enc + GEPS));
        }

        // jnp.argmax first-max tie-break: arg = 1 iff l2 > l1
        float r0, r1;
        if (l[1] > l[0]) { r0 = 0.0f;   r1 = gv[9]; }
        else             { r0 = gv[4];  r1 = 0.0f;  }
        app[tid] = fmaxf(r0, r1);

        float d;
        d = gv[0] - pv[0]; s += d * d * r0 * LAMB_COORD;
        d = gv[1] - pv[1]; s += d * d * r0 * LAMB_COORD;
        d = gv[5] - pv[5]; s += d * d * r1 * LAMB_COORD;
        d = gv[6] - pv[6]; s += d * d * r1 * LAMB_COORD;
        d = sqrtf(gv[2]) - sqrtf(pv[2]); s += d * d * r0 * LAMB_COORD;
        d = sqrtf(gv[3]) - sqrtf(pv[3]); s += d * d * r0 * LAMB_COORD;
        d = sqrtf(gv[7]) - sqrtf(pv[7]); s += d * d * r1 * LAMB_COORD;
        d = sqrtf(gv[8]) - sqrtf(pv[8]); s += d * d * r1 * LAMB_COORD;
        d = gv[4] - pv[4]; { float d2 = d * d; s += d2 * r0 + d2 * (1.0f - r0) * LAMB_NOOBJ; }
        d = gv[9] - pv[9]; { float d2 = d * d; s += d2 * r1 + d2 * (1.0f - r1) * LAMB_NOOBJ; }
    }
    __syncthreads();

    // ---- Class: consume 980 float2 from LDS with app mask ----
    // q-th class float2 (q = rr*490 + j): float offset = 490 + 2q + 490*rr.
    // hw = (2q) mod 49 (since 980 = 20*49, same formula both records).
    #pragma unroll
    for (int k = 0; k < 4; ++k) {
        int q = tid + k * 256;
        if (q < CLS2) {
            int rr  = (q >= 490) ? 1 : 0;
            int off = 490 + 2 * q + 490 * rr;
            int hw  = (2 * q) % 49;
            int hw1 = (hw == 48) ? 0 : hw + 1;
            float2 gv2 = *(const float2*)(lg + off);
            float2 pv2 = *(const float2*)(lp + off);
            float a0 = app[rr * 49 + hw];
            float a1 = app[rr * 49 + hw1];
            float d0 = gv2.x - pv2.x;
            float d1 = gv2.y - pv2.y;
            s += d0 * d0 * a0 + d1 * d1 * a1;
        }
    }

    // ---- Reduce: wave shuffle -> LDS -> one atomic per block ----
    #pragma unroll
    for (int off = 32; off > 0; off >>= 1)
        s += __shfl_down(s, off, 64);

    const int lane = tid & 63;
    const int wid  = tid >> 6;
    if (lane == 0) wsum[wid] = s;
    __syncthreads();
    if (tid == 0) {
        atomicAdd(out, wsum[0] + wsum[1] + wsum[2] + wsum[3]);
    }
}

extern "C" void kernel_launch(void* const* d_in, const int* in_sizes, int n_in,
                              void* d_out, int out_size, void* d_ws, size_t ws_size,
                              hipStream_t stream) {
    const float* gt   = (const float*)d_in[0];
    const float* pred = (const float*)d_in[1];
    float* out = (float*)d_out;

    const int B = in_sizes[0] / RECF;    // 16384
    const int grid = B / 2;              // 8192 blocks, 2 records each

    hipMemsetAsync(out, 0, sizeof(float) * out_size, stream);
    yolo_loss_kernel<<<grid, 256, 0, stream>>>(gt, pred, out);
}

// Round 10
// 61.217 us; speedup vs baseline: 1.9758x; 1.9758x over previous
//
#include <hip/hip_runtime.h>

#define LAMB_COORD 5.0f
#define LAMB_NOOBJ 0.5f
#define GEPS 1e-7f

// gt/pred: (B=16384, C=30, H=7, W=7) fp32. One thread per cell (b,hw).
// R3 structure verbatim (all 60 channel loads clustered above one
// sched_barrier(0)), with ONE change: __launch_bounds__(256, 4).
// 4 waves/EU -> VGPR budget 128 -> the allocator can keep all ~60 load
// results live in VGPRs (no AGPR/scratch shuffling, no intra-batch waits),
// giving ~15 KB in flight per wave during the load phase.
// ncells = 16384*49 = 802816 = 3136 * 256 exactly -> no tail predicate.

__global__ __launch_bounds__(256, 4) void yolo_loss_kernel(
        const float* __restrict__ gt, const float* __restrict__ pred,
        float* __restrict__ out) {
    const int i  = blockIdx.x * 256 + threadIdx.x;
    const int b  = i / 49;
    const int hw = i - b * 49;
    const float* __restrict__ g = gt   + (size_t)b * 1470 + hw;
    const float* __restrict__ p = pred + (size_t)b * 1470 + hw;

    // ---- Issue ALL 60 independent loads before any use ----
    float gv[30], pv[30];
    #pragma unroll
    for (int c = 0; c < 30; ++c) gv[c] = g[c * 49];
    #pragma unroll
    for (int c = 0; c < 30; ++c) pv[c] = p[c * 49];
    __builtin_amdgcn_sched_barrier(0);  // keep loads clustered above compute

    // ---- GIoU(gt box, pred box k) for k=0 (ch 0..3) and k=1 (ch 5..8) ----
    const float gx1 = gv[0], gy1 = gv[1];
    const float gx2 = gv[0] + gv[2], gy2 = gv[1] + gv[3];
    const float ga  = (gx2 - gx1) * (gy2 - gy1);

    float l[2];
    #pragma unroll
    for (int k = 0; k < 2; ++k) {
        const int o = k * 5;
        float px1 = pv[o + 0], py1 = pv[o + 1];
        float px2 = px1 + pv[o + 2], py2 = py1 + pv[o + 3];
        float ix1 = fmaxf(gx1, px1), iy1 = fmaxf(gy1, py1);
        float ix2 = fminf(gx2, px2), iy2 = fminf(gy2, py2);
        float inter = fmaxf(ix2 - ix1, 0.0f) * fmaxf(iy2 - iy1, 0.0f);
        float pa  = (px2 - px1) * (py2 - py1);
        float uni = ga + pa - inter;
        float iou = inter / (uni + GEPS);
        float cx1 = fminf(gx1, px1), cy1 = fminf(gy1, py1);
        float cx2 = fmaxf(gx2, px2), cy2 = fmaxf(gy2, py2);
        float enc = (cx2 - cx1) * (cy2 - cy1);
        l[k] = 1.0f - (iou - (enc - uni) / (enc + GEPS));
    }

    // jnp.argmax first-max tie-break: arg = 1 iff l2 > l1
    float r0, r1;
    if (l[1] > l[0]) { r0 = 0.0f;   r1 = gv[9]; }
    else             { r0 = gv[4];  r1 = 0.0f;  }
    const float appears = fmaxf(r0, r1);

    float s = 0.0f;
    float d;
    d = gv[0] - pv[0]; s += d * d * r0 * LAMB_COORD;
    d = gv[1] - pv[1]; s += d * d * r0 * LAMB_COORD;
    d = gv[5] - pv[5]; s += d * d * r1 * LAMB_COORD;
    d = gv[6] - pv[6]; s += d * d * r1 * LAMB_COORD;
    d = sqrtf(gv[2]) - sqrtf(pv[2]); s += d * d * r0 * LAMB_COORD;
    d = sqrtf(gv[3]) - sqrtf(pv[3]); s += d * d * r0 * LAMB_COORD;
    d = sqrtf(gv[7]) - sqrtf(pv[7]); s += d * d * r1 * LAMB_COORD;
    d = sqrtf(gv[8]) - sqrtf(pv[8]); s += d * d * r1 * LAMB_COORD;
    d = gv[4] - pv[4]; { float d2 = d * d; s += d2 * r0 + d2 * (1.0f - r0) * LAMB_NOOBJ; }
    d = gv[9] - pv[9]; { float d2 = d * d; s += d2 * r1 + d2 * (1.0f - r1) * LAMB_NOOBJ; }

    float cls = 0.0f;
    #pragma unroll
    for (int c = 10; c < 30; ++c) {
        float dc = gv[c] - pv[c];
        cls += dc * dc;
    }
    s += cls * appears;

    // ---- Reduce: 64-lane wave shuffle -> LDS -> one atomic per block ----
    #pragma unroll
    for (int off = 32; off > 0; off >>= 1)
        s += __shfl_down(s, off, 64);

    __shared__ float wsum[4];
    const int lane = threadIdx.x & 63;
    const int wid  = threadIdx.x >> 6;
    if (lane == 0) wsum[wid] = s;
    __syncthreads();
    if (threadIdx.x == 0) {
        atomicAdd(out, wsum[0] + wsum[1] + wsum[2] + wsum[3]);
    }
}

extern "C" void kernel_launch(void* const* d_in, const int* in_sizes, int n_in,
                              void* d_out, int out_size, void* d_ws, size_t ws_size,
                              hipStream_t stream) {
    const float* gt   = (const float*)d_in[0];
    const float* pred = (const float*)d_in[1];
    float* out = (float*)d_out;

    const int B = in_sizes[0] / 1470;    // 16384
    const int ncells = B * 49;           // 802816 = 3136 * 256
    const int grid = ncells / 256;       // 3136

    hipMemsetAsync(out, 0, sizeof(float) * out_size, stream);
    yolo_loss_kernel<<<grid, 256, 0, stream>>>(gt, pred, out);
}

// Round 11
// 47.900 us; speedup vs baseline: 2.5250x; 1.2780x over previous
//
#include <hip/hip_runtime.h>

#define LAMB_COORD 5.0f
#define LAMB_NOOBJ 0.5f
#define GEPS 1e-7f

// gt/pred: (B=16384, C=30, H=7, W=7) fp32. Record = 1470 floats = 30ch x 49 cells.
// R7 structure with loop depth: 1024 blocks x 256 threads, RPB=16 records/block.
// Phase A: ~3-trip cell loop (784 cells), unroll 2, dual accumulators ->
//          across-iteration load/compute overlap (software pipelining).
// Phase B: 16-trip record loop streaming class region as contiguous float2
//          (byte-identical math to R7).
// __launch_bounds__(256,4): 4 waves/EU = 16 waves/CU, VGPR budget 128.

#define RPB   16
#define CELLS (RPB * 49)          // 784
#define CLS2R 490                 // float2 per record class region

__global__ __launch_bounds__(256, 4) void yolo_loss_kernel(
        const float* __restrict__ gt, const float* __restrict__ pred,
        float* __restrict__ out) {
    __shared__ float app[CELLS];
    __shared__ float wsum[4];

    const int tid = threadIdx.x;
    const size_t rec0 = (size_t)blockIdx.x * RPB;

    float s0 = 0.0f, s1 = 0.0f;

    // ---- Phase A: front (channels 0..9), one cell per thread-iteration ----
    #pragma unroll 2
    for (int cell = tid; cell < CELLS; cell += 256) {
        const int rr = cell / 49;
        const int hw = cell - rr * 49;
        const float* __restrict__ g = gt   + (rec0 + rr) * 1470 + hw;
        const float* __restrict__ p = pred + (rec0 + rr) * 1470 + hw;

        float gv[10], pv[10];
        #pragma unroll
        for (int c = 0; c < 10; ++c) { gv[c] = g[c * 49]; pv[c] = p[c * 49]; }

        const float gx1 = gv[0], gy1 = gv[1];
        const float gx2 = gv[0] + gv[2], gy2 = gv[1] + gv[3];
        const float ga  = (gx2 - gx1) * (gy2 - gy1);

        float l[2];
        #pragma unroll
        for (int k = 0; k < 2; ++k) {
            const int o = k * 5;
            float px1 = pv[o + 0], py1 = pv[o + 1];
            float px2 = px1 + pv[o + 2], py2 = py1 + pv[o + 3];
            float ix1 = fmaxf(gx1, px1), iy1 = fmaxf(gy1, py1);
            float ix2 = fminf(gx2, px2), iy2 = fminf(gy2, py2);
            float inter = fmaxf(ix2 - ix1, 0.0f) * fmaxf(iy2 - iy1, 0.0f);
            float pa  = (px2 - px1) * (py2 - py1);
            float uni = ga + pa - inter;
            float iou = inter / (uni + GEPS);
            float cx1 = fminf(gx1, px1), cy1 = fminf(gy1, py1);
            float cx2 = fmaxf(gx2, px2), cy2 = fmaxf(gy2, py2);
            float enc = (cx2 - cx1) * (cy2 - cy1);
            l[k] = 1.0f - (iou - (enc - uni) / (enc + GEPS));
        }

        // jnp.argmax first-max tie-break: arg = 1 iff l2 > l1
        float r0, r1;
        if (l[1] > l[0]) { r0 = 0.0f;   r1 = gv[9]; }
        else             { r0 = gv[4];  r1 = 0.0f;  }
        app[cell] = fmaxf(r0, r1);

        float t = 0.0f;
        float d;
        d = gv[0] - pv[0]; t += d * d * r0 * LAMB_COORD;
        d = gv[1] - pv[1]; t += d * d * r0 * LAMB_COORD;
        d = gv[5] - pv[5]; t += d * d * r1 * LAMB_COORD;
        d = gv[6] - pv[6]; t += d * d * r1 * LAMB_COORD;
        d = sqrtf(gv[2]) - sqrtf(pv[2]); t += d * d * r0 * LAMB_COORD;
        d = sqrtf(gv[3]) - sqrtf(pv[3]); t += d * d * r0 * LAMB_COORD;
        d = sqrtf(gv[7]) - sqrtf(pv[7]); t += d * d * r1 * LAMB_COORD;
        d = sqrtf(gv[8]) - sqrtf(pv[8]); t += d * d * r1 * LAMB_COORD;
        d = gv[4] - pv[4]; { float d2 = d * d; t += d2 * r0 + d2 * (1.0f - r0) * LAMB_NOOBJ; }
        d = gv[9] - pv[9]; { float d2 = d * d; t += d2 * r1 + d2 * (1.0f - r1) * LAMB_NOOBJ; }

        if ((cell >> 8) & 1) s1 += t; else s0 += t;
    }
    float s = s0 + s1;
    __syncthreads();

    // ---- Phase B: class stream (channels 10..29), R7 structure ----
    // q0 = tid, q1 = tid + 256 (< 490). hw(q) = (2q) mod 49, loop-invariant.
    const int q0 = tid;
    const int q1 = tid + 256;
    int h0 = (2 * q0) % 49;
    int h0n = (h0 == 48) ? 0 : h0 + 1;
    int h1 = (2 * q1) % 49;
    int h1n = (h1 == 48) ? 0 : h1 + 1;
    const bool do_q1 = (q1 < CLS2R);

    #pragma unroll 4
    for (int rr = 0; rr < RPB; ++rr) {
        const float2* __restrict__ gc = (const float2*)(gt   + (rec0 + rr) * 1470 + 490);
        const float2* __restrict__ pc = (const float2*)(pred + (rec0 + rr) * 1470 + 490);
        const int ab = rr * 49;

        float2 ga2 = gc[q0];
        float2 pa2 = pc[q0];
        float a0 = app[ab + h0];
        float a1 = app[ab + h0n];
        float d0 = ga2.x - pa2.x;
        float d1 = ga2.y - pa2.y;
        s += d0 * d0 * a0 + d1 * d1 * a1;

        if (do_q1) {
            float2 gb2 = gc[q1];
            float2 pb2 = pc[q1];
            float b0 = app[ab + h1];
            float b1 = app[ab + h1n];
            float e0 = gb2.x - pb2.x;
            float e1 = gb2.y - pb2.y;
            s += e0 * e0 * b0 + e1 * e1 * b1;
        }
    }

    // ---- Reduce: wave shuffle -> LDS -> one atomic per block ----
    #pragma unroll
    for (int off = 32; off > 0; off >>= 1)
        s += __shfl_down(s, off, 64);

    const int lane = tid & 63;
    const int wid  = tid >> 6;
    if (lane == 0) wsum[wid] = s;
    __syncthreads();
    if (tid == 0) {
        atomicAdd(out, wsum[0] + wsum[1] + wsum[2] + wsum[3]);
    }
}

extern "C" void kernel_launch(void* const* d_in, const int* in_sizes, int n_in,
                              void* d_out, int out_size, void* d_ws, size_t ws_size,
                              hipStream_t stream) {
    const float* gt   = (const float*)d_in[0];
    const float* pred = (const float*)d_in[1];
    float* out = (float*)d_out;

    const int B = in_sizes[0] / 1470;    // 16384
    const int grid = B / RPB;            // 1024

    hipMemsetAsync(out, 0, sizeof(float) * out_size, stream);
    yolo_loss_kernel<<<grid, 256, 0, stream>>>(gt, pred, out);
}

// Round 12
// 40.408 us; speedup vs baseline: 2.9932x; 1.1854x over previous
//
#include <hip/hip_runtime.h>

#define LAMB_COORD 5.0f
#define LAMB_NOOBJ 0.5f
#define GEPS 1e-7f

// gt/pred: (B=16384, C=30, H=7, W=7) fp32. Record = 1470 floats = 30ch x 49 cells.
// R11 gradient continued: 512 blocks x 512 threads (8 waves), RPB=32 records/block.
//   -> same total waves as R11 (4096) but phase B is a 32-trip unconditional
//      stream (tid<490 guard hoisted out; no per-trip branch) and phase A keeps
//      ~3 trips with unroll 2 + dual accumulators.
// __launch_bounds__(512,4): 16 waves/CU target = 2 blocks/CU (grid 512 = exact).

#define RPB   32
#define CELLS (RPB * 49)          // 1568
#define CLS2R 490                 // float2 per record class region

__global__ __launch_bounds__(512, 4) void yolo_loss_kernel(
        const float* __restrict__ gt, const float* __restrict__ pred,
        float* __restrict__ out) {
    __shared__ float app[CELLS];  // 6272 B
    __shared__ float wsum[8];

    const int tid = threadIdx.x;
    const size_t rec0 = (size_t)blockIdx.x * RPB;

    float s0 = 0.0f, s1 = 0.0f;

    // ---- Phase A: front (channels 0..9), one cell per thread-iteration ----
    #pragma unroll 2
    for (int cell = tid; cell < CELLS; cell += 512) {
        const int rr = cell / 49;
        const int hw = cell - rr * 49;
        const float* __restrict__ g = gt   + (rec0 + rr) * 1470 + hw;
        const float* __restrict__ p = pred + (rec0 + rr) * 1470 + hw;

        float gv[10], pv[10];
        #pragma unroll
        for (int c = 0; c < 10; ++c) { gv[c] = g[c * 49]; pv[c] = p[c * 49]; }

        const float gx1 = gv[0], gy1 = gv[1];
        const float gx2 = gv[0] + gv[2], gy2 = gv[1] + gv[3];
        const float ga  = (gx2 - gx1) * (gy2 - gy1);

        float l[2];
        #pragma unroll
        for (int k = 0; k < 2; ++k) {
            const int o = k * 5;
            float px1 = pv[o + 0], py1 = pv[o + 1];
            float px2 = px1 + pv[o + 2], py2 = py1 + pv[o + 3];
            float ix1 = fmaxf(gx1, px1), iy1 = fmaxf(gy1, py1);
            float ix2 = fminf(gx2, px2), iy2 = fminf(gy2, py2);
            float inter = fmaxf(ix2 - ix1, 0.0f) * fmaxf(iy2 - iy1, 0.0f);
            float pa  = (px2 - px1) * (py2 - py1);
            float uni = ga + pa - inter;
            float iou = inter / (uni + GEPS);
            float cx1 = fminf(gx1, px1), cy1 = fminf(gy1, py1);
            float cx2 = fmaxf(gx2, px2), cy2 = fmaxf(gy2, py2);
            float enc = (cx2 - cx1) * (cy2 - cy1);
            l[k] = 1.0f - (iou - (enc - uni) / (enc + GEPS));
        }

        // jnp.argmax first-max tie-break: arg = 1 iff l2 > l1
        float r0, r1;
        if (l[1] > l[0]) { r0 = 0.0f;   r1 = gv[9]; }
        else             { r0 = gv[4];  r1 = 0.0f;  }
        app[cell] = fmaxf(r0, r1);

        float t = 0.0f;
        float d;
        d = gv[0] - pv[0]; t += d * d * r0 * LAMB_COORD;
        d = gv[1] - pv[1]; t += d * d * r0 * LAMB_COORD;
        d = gv[5] - pv[5]; t += d * d * r1 * LAMB_COORD;
        d = gv[6] - pv[6]; t += d * d * r1 * LAMB_COORD;
        d = sqrtf(gv[2]) - sqrtf(pv[2]); t += d * d * r0 * LAMB_COORD;
        d = sqrtf(gv[3]) - sqrtf(pv[3]); t += d * d * r0 * LAMB_COORD;
        d = sqrtf(gv[7]) - sqrtf(pv[7]); t += d * d * r1 * LAMB_COORD;
        d = sqrtf(gv[8]) - sqrtf(pv[8]); t += d * d * r1 * LAMB_COORD;
        d = gv[4] - pv[4]; { float d2 = d * d; t += d2 * r0 + d2 * (1.0f - r0) * LAMB_NOOBJ; }
        d = gv[9] - pv[9]; { float d2 = d * d; t += d2 * r1 + d2 * (1.0f - r1) * LAMB_NOOBJ; }

        if ((cell >> 9) & 1) s1 += t; else s0 += t;
    }
    float s = s0 + s1;
    __syncthreads();

    // ---- Phase B: class stream (channels 10..29), 32-trip record loop ----
    // q = tid (< 490). hw(q) = (2q) mod 49, loop-invariant.
    if (tid < CLS2R) {
        const int q = tid;
        int h0 = (2 * q) % 49;
        int h0n = (h0 == 48) ? 0 : h0 + 1;

        #pragma unroll 4
        for (int rr = 0; rr < RPB; ++rr) {
            const float2* __restrict__ gc = (const float2*)(gt   + (rec0 + rr) * 1470 + 490);
            const float2* __restrict__ pc = (const float2*)(pred + (rec0 + rr) * 1470 + 490);
            const int ab = rr * 49;

            float2 ga2 = gc[q];
            float2 pa2 = pc[q];
            float a0 = app[ab + h0];
            float a1 = app[ab + h0n];
            float d0 = ga2.x - pa2.x;
            float d1 = ga2.y - pa2.y;
            s += d0 * d0 * a0 + d1 * d1 * a1;
        }
    }

    // ---- Reduce: wave shuffle -> LDS -> one atomic per block ----
    #pragma unroll
    for (int off = 32; off > 0; off >>= 1)
        s += __shfl_down(s, off, 64);

    const int lane = tid & 63;
    const int wid  = tid >> 6;
    if (lane == 0) wsum[wid] = s;
    __syncthreads();
    if (tid == 0) {
        float b = 0.0f;
        #pragma unroll
        for (int w = 0; w < 8; ++w) b += wsum[w];
        atomicAdd(out, b);
    }
}

extern "C" void kernel_launch(void* const* d_in, const int* in_sizes, int n_in,
                              void* d_out, int out_size, void* d_ws, size_t ws_size,
                              hipStream_t stream) {
    const float* gt   = (const float*)d_in[0];
    const float* pred = (const float*)d_in[1];
    float* out = (float*)d_out;

    const int B = in_sizes[0] / 1470;    // 16384
    const int grid = B / RPB;            // 512

    hipMemsetAsync(out, 0, sizeof(float) * out_size, stream);
    yolo_loss_kernel<<<grid, 512, 0, stream>>>(gt, pred, out);
}